// Round 1
// 487.072 us; speedup vs baseline: 1.0960x; 1.0960x over previous
//
#include <hip/hip_runtime.h>
#include <stdint.h>

typedef unsigned int u32;
typedef unsigned long long u64;

#define BB 2
#define CC 32
#define DD 64
#define HH 128
#define WW 128
#define SS (DD*HH*WW)        /* 1048576 */
#define NN (BB*SS)           /* 2097152 */
#define NQ (NN/4)            /* 524288 */
#define NWORDS (NN/64)       /* 32768 */
#define EPSF 1e-12f
#define TOPN 250u

struct Ctrl {
  u32 done4, tie, pad0, pad1;
};

struct Acc {
  double ce, tp, fp, fn;
  double stdsum[CC];
  double pos_num, mis_num, fin_num;
  u64 cnt, mcnt, fcnt;
};

// ---------- reduction helpers ----------
__device__ __forceinline__ float waveRedF(float v){
#pragma unroll
  for (int o = 32; o; o >>= 1) v += __shfl_xor(v, o);
  return v;
}
__device__ __forceinline__ u32 waveRedU(u32 v){
#pragma unroll
  for (int o = 32; o; o >>= 1) v += __shfl_xor(v, o);
  return v;
}
__device__ __forceinline__ void red_d(double* dst, float v, volatile float* sh){
  int lane = threadIdx.x & 63, wid = threadIdx.x >> 6;
  v = waveRedF(v);
  if (lane == 0) sh[wid] = v;
  __syncthreads();
  if (threadIdx.x == 0){
    float t = 0.f;
    for (int i = 0; i < (int)(blockDim.x >> 6); i++) t += sh[i];
    atomicAdd(dst, (double)t);
  }
  __syncthreads();
}
__device__ __forceinline__ void red_u(u64* dst, u32 v, volatile u32* sh){
  int lane = threadIdx.x & 63, wid = threadIdx.x >> 6;
  v = waveRedU(v);
  if (lane == 0) sh[wid] = v;
  __syncthreads();
  if (threadIdx.x == 0){
    u32 t = 0;
    for (int i = 0; i < (int)(blockDim.x >> 6); i++) t += sh[i];
    atomicAdd(dst, (u64)t);
  }
  __syncthreads();
}

__device__ __forceinline__ u32 sortkey(float f){
  u32 u = __float_as_uint(f);
  return (u & 0x80000000u) ? ~u : (u | 0x80000000u);
}

// Redundant per-block top-k bin selection from a finalized global histogram.
__device__ __forceinline__ void select_top(const u32* __restrict__ hist, u32 nbins,
                                           u32 k, u32* shres, u32* binOut, u32* kremOut){
  __syncthreads();
  if (threadIdx.x < 64){
    int lane = threadIdx.x;
    u32 running = 0; bool found = false;
    for (u32 chunk = 0; chunk * 64 < nbins && !found; chunk++){
      int bin = (int)nbins - 1 - (int)(chunk * 64 + (u32)lane);
      u32 val = (bin >= 0) ? hist[bin] : 0u;
      u32 p = val;
#pragma unroll
      for (int o = 1; o < 64; o <<= 1){ u32 t = __shfl_up(p, o); if (lane >= o) p += t; }
      u32 tot = __shfl(p, 63);
      u32 incl = running + p, excl = incl - val;
      bool hit = (excl < k) && (incl >= k);
      u64 mb = __ballot(hit);
      if (mb){
        int hl = __ffsll((unsigned long long)mb) - 1;
        if (lane == hl){ shres[0] = (u32)bin; shres[1] = k - excl; }
        found = true;
      } else running += tot;
    }
    if (!found && lane == 0){ shres[0] = 0; shres[1] = k; }
  }
  __syncthreads();
  *binOut = shres[0]; *kremOut = shres[1];
}

// ---------- K0: pbits from tgt + per-block pos counts + zero accumulators ----------
// grid 512 x 256. Each block packs 4096 voxels -> 64 u64 words.
// No atomics on acc here, so block 0 can zero h1/h2/ctrl/acc in the same kernel
// (consumers are all in LATER kernels) -> hipMemsetAsync dispatch eliminated.
__global__ __launch_bounds__(256) void k_pre(const int* __restrict__ tgt,
                                             u64* __restrict__ pbits,
                                             u32* __restrict__ cntArr,
                                             u32* __restrict__ zptr, u32 zwords){
  __shared__ u32 nibsh[256];
  __shared__ u32 shu[4];
  if (blockIdx.x == 0){
    for (u32 i = threadIdx.x; i < zwords; i += 256u) zptr[i] = 0;
  }
  u32 cnt = 0;
#pragma unroll 1
  for (u32 it = 0; it < 4; it++){
    u32 q = blockIdx.x * 1024u + it * 256u + threadIdx.x;   // quad index
    int4 l4 = *(const int4*)(tgt + q * 4u);
    u32 nib = (l4.x ? 1u : 0u) | (l4.y ? 2u : 0u) | (l4.z ? 4u : 0u) | (l4.w ? 8u : 0u);
    cnt += __popc(nib);
    __syncthreads();             // protect nibsh reuse across iterations
    nibsh[threadIdx.x] = nib;
    __syncthreads();
    if (threadIdx.x < 16){
      u64 o = 0;
#pragma unroll
      for (int j = 0; j < 16; j++)
        o |= (u64)(nibsh[threadIdx.x * 16 + j] & 0xFu) << (4 * j);
      pbits[blockIdx.x * 64u + it * 16u + threadIdx.x] = o;
    }
  }
  int lane = threadIdx.x & 63, wid = threadIdx.x >> 6;
  cnt = waveRedU(cnt);
  if (lane == 0) shu[wid] = cnt;
  __syncthreads();
  if (threadIdx.x == 0) cntArr[blockIdx.x] = shu[0] + shu[1] + shu[2] + shu[3];
}

// ---------- K1: fused CE/dice + channel-major pos-sum of feature ----------
// Blocks 0..63: CE/dice over net (16 MB), labels from pbits (no tgt re-read).
// Blocks 64..1087: std pos-sums, each reading a SEQUENTIAL 256-KB feature run.
// CE blocks dispatch first so their 16 MB read hides under the 256 MB stream.
__global__ __launch_bounds__(256) void k_ce_std(const float* __restrict__ feat,
                                                const float* __restrict__ net,
                                                const u64* __restrict__ pbits, Acc* acc){
  __shared__ float sh[16];
  if (blockIdx.x < 64u){
    u32 bid = blockIdx.x;
    float ce = 0.f, tp = 0.f, fp = 0.f, fnn = 0.f;
#pragma unroll 1
    for (u32 it = 0; it < 32; it++){
      u32 q = bid * 8192u + it * 256u + threadIdx.x;        // quad index
      u32 nib = (u32)(pbits[q >> 4] >> ((q & 15u) << 2)) & 0xFu;
      u32 v = q * 4u;
      u32 b = v >> 20, s = v & (SS - 1);
      const float* nb = net + (size_t)(b * 2) * SS + s;
      float4 x0 = *(const float4*)(nb);
      float4 x1 = *(const float4*)(nb + SS);
      float xs0[4] = {x0.x, x0.y, x0.z, x0.w};
      float xs1[4] = {x1.x, x1.y, x1.z, x1.w};
#pragma unroll
      for (int j = 0; j < 4; j++){
        int lab = (nib >> j) & 1;
        float m = fmaxf(xs0[j], xs1[j]);
        float lse = m + logf(expf(xs0[j] - m) + expf(xs1[j] - m));
        ce += lse - (lab ? xs1[j] : xs0[j]);
        float p1 = expf(xs1[j] - lse);
        if (lab){ tp += p1; fnn += 1.0f - p1; } else fp += p1;
      }
    }
    int lane = threadIdx.x & 63, wid = threadIdx.x >> 6;
    ce = waveRedF(ce); tp = waveRedF(tp); fp = waveRedF(fp); fnn = waveRedF(fnn);
    if (lane == 0){ sh[wid] = ce; sh[4 + wid] = tp; sh[8 + wid] = fp; sh[12 + wid] = fnn; }
    __syncthreads();
    if (threadIdx.x == 0){
      atomicAdd(&acc->ce, (double)(sh[0] + sh[1] + sh[2] + sh[3]));
      atomicAdd(&acc->tp, (double)(sh[4] + sh[5] + sh[6] + sh[7]));
      atomicAdd(&acc->fp, (double)(sh[8] + sh[9] + sh[10] + sh[11]));
      atomicAdd(&acc->fn, (double)(sh[12] + sh[13] + sh[14] + sh[15]));
    }
  } else {
    u32 bx = blockIdx.x - 64u;
    u32 c = bx & 31u;
    u32 chunk = bx >> 5;                // 0..31
    u32 vbase = chunk * 65536u;
    u32 b = vbase >> 20;
    u32 s0 = vbase & (SS - 1);
    const float* fp_ = feat + (size_t)b * CC * SS + (size_t)c * SS + s0;
    const u64* pb = pbits + (vbase >> 6);
    float a = 0.f;
#pragma unroll 8
    for (u32 i = 0; i < 64; i++){
      u32 off = i * 1024u + threadIdx.x * 4u;
      float4 f = *(const float4*)(fp_ + off);
      u32 bits = (u32)(pb[off >> 6] >> (off & 63u)) & 0xFu;
      if (bits & 1u) a += f.x;
      if (bits & 2u) a += f.y;
      if (bits & 4u) a += f.z;
      if (bits & 8u) a += f.w;
    }
    int lane = threadIdx.x & 63, wid = threadIdx.x >> 6;
    a = waveRedF(a);
    if (lane == 0) sh[wid] = a;
    __syncthreads();
    if (threadIdx.x == 0)
      atomicAdd(&acc->stdsum[c], (double)(sh[0] + sh[1] + sh[2] + sh[3]));
  }
}

// ---------- K3: sim via register-blocked channel-outer loop ----------
// Each block owns 4096 voxels; per channel it reads a dense 16-KB window.
// dot/n2 live in registers (4 float4 each). Fused: pos_num + level-1 hist.
__global__ __launch_bounds__(256) void k_sim(const float* __restrict__ feat,
                                             const u64* __restrict__ pbits,
                                             const u32* __restrict__ cntArr,
                                             Acc* acc, float* __restrict__ sim,
                                             u32* __restrict__ h1){
  __shared__ float st[CC];
  __shared__ u32 lh[2048];
  __shared__ float shf[4];
  __shared__ u32 scnt;
  if (threadIdx.x < 64){
    u32 sc = 0;
#pragma unroll
    for (int i = 0; i < 8; i++) sc += cntArr[threadIdx.x * 8 + i];
    sc = waveRedU(sc);
    if (threadIdx.x == 0) scnt = sc;
  }
  __syncthreads();
  u32 cnt = scnt;
  if (blockIdx.x == 0 && threadIdx.x == 0) acc->cnt = (u64)cnt;
  {
    float sv = 0.f;
    if (threadIdx.x < CC && cnt) sv = (float)(acc->stdsum[threadIdx.x] / (double)cnt);
    if (threadIdx.x < 64){
      float t = waveRedF(sv * sv);
      float d = fmaxf(sqrtf(t), EPSF);
      if (threadIdx.x < CC) st[threadIdx.x] = sv / d;
    }
  }
  for (u32 i = threadIdx.x; i < 2048u; i += 256u) lh[i] = 0;
  __syncthreads();
  u32 vbase = blockIdx.x * 4096u;
  u32 b = vbase >> 20;
  u32 s0 = vbase & (SS - 1);
  const float* fp = feat + (size_t)b * CC * SS + s0;
  float4 dt[4], n2[4];
#pragma unroll
  for (int g = 0; g < 4; g++){
    dt[g].x = dt[g].y = dt[g].z = dt[g].w = 0.f;
    n2[g].x = n2[g].y = n2[g].z = n2[g].w = 0.f;
  }
#pragma unroll 2
  for (u32 c = 0; c < CC; c++){
    float w = st[c];
    const float* fc = fp + (size_t)c * SS;
    float4 f[4];
#pragma unroll
    for (int g = 0; g < 4; g++)
      f[g] = *(const float4*)(fc + (u32)g * 1024u + threadIdx.x * 4u);
#pragma unroll
    for (int g = 0; g < 4; g++){
      dt[g].x += f[g].x * w; dt[g].y += f[g].y * w;
      dt[g].z += f[g].z * w; dt[g].w += f[g].w * w;
      n2[g].x += f[g].x * f[g].x; n2[g].y += f[g].y * f[g].y;
      n2[g].z += f[g].z * f[g].z; n2[g].w += f[g].w * f[g].w;
    }
  }
  float pn = 0.f;
#pragma unroll
  for (int g = 0; g < 4; g++){
    u32 off = (u32)g * 1024u + threadIdx.x * 4u;
    u32 v = vbase + off;
    float4 sm;
    sm.x = dt[g].x / fmaxf(sqrtf(n2[g].x), EPSF);
    sm.y = dt[g].y / fmaxf(sqrtf(n2[g].y), EPSF);
    sm.z = dt[g].z / fmaxf(sqrtf(n2[g].z), EPSF);
    sm.w = dt[g].w / fmaxf(sqrtf(n2[g].w), EPSF);
    *(float4*)(sim + v) = sm;
    u32 bits = (u32)(pbits[v >> 6] >> (v & 63u)) & 0xFu;
    float ss[4] = {sm.x, sm.y, sm.z, sm.w};
#pragma unroll
    for (int j = 0; j < 4; j++){
      if ((bits >> j) & 1u) pn += 1.f - ss[j];
      else atomicAdd(&lh[sortkey(ss[j]) >> 21], 1u);
    }
  }
  __syncthreads();
  for (u32 i = threadIdx.x; i < 2048u; i += 256u)
    if (lh[i]) atomicAdd(&h1[i], lh[i]);
  red_d(&acc->pos_num, pn, shf);
}

// ---------- fused W+H slab dilation as a device function ----------
__device__ __forceinline__ void dilwh_slab(const u64* __restrict__ in, u64* __restrict__ out,
                                           u32 slab, u64* arr){
  u32 base = slab * 256u;
  int t = threadIdx.x;
  if (t < 128){
    u64 lo = in[base + 2 * t], hi = in[base + 2 * t + 1];
    u64 al = lo, ah = hi;
#pragma unroll
    for (int i = 0; i < 10; i++){ u64 c = al >> 63; ah = ah | (ah << 1) | c; al = al | (al << 1); }
    u64 bl = lo, bh = hi;
#pragma unroll
    for (int i = 0; i < 10; i++){ u64 c = bh << 63; bl = bl | (bl >> 1) | c; bh = bh | (bh >> 1); }
    arr[2 * t] = al | bl;
    arr[2 * t + 1] = ah | bh;
  }
  __syncthreads();
  int h = t >> 1, wj = t & 1;
  int h0 = h - 10 > 0 ? h - 10 : 0;
  int h1 = h + 10 < 127 ? h + 10 : 127;
  u64 o = 0;
  for (int hh = h0; hh <= h1; hh++) o |= arr[2 * hh + wj];
  out[base + (u32)t] = o;
  __syncthreads();
}

// ---------- W+H dilation standalone (for HS) ----------
__global__ __launch_bounds__(256) void k_dilwh(const u64* __restrict__ in, u64* __restrict__ out){
  __shared__ u64 arr[256];
  dilwh_slab(in, out, blockIdx.x, arr);
}

// ---------- level-2 histogram + (blocks<128) W+H dilation of P ----------
__global__ __launch_bounds__(256) void k_histL2(const float* __restrict__ sim,
                                                const u64* __restrict__ pbits,
                                                const u32* __restrict__ h1,
                                                u32* __restrict__ h2,
                                                const u64* __restrict__ P,
                                                u64* __restrict__ T1P){
  __shared__ u64 arr[256];
  __shared__ u32 lh[2048];
  __shared__ u32 shres[2];
  if (blockIdx.x < 128u) dilwh_slab(P, T1P, blockIdx.x, arr);
  u32 p1, k1;
  select_top(h1, 2048, TOPN, shres, &p1, &k1);
  for (u32 i = threadIdx.x; i < 2048u; i += 256u) lh[i] = 0;
  __syncthreads();
  const u32 stride = 512u * 256u;
#pragma unroll 1
  for (u32 it = 0; it < 4; it++){
    u32 q = blockIdx.x * 256u + threadIdx.x + it * stride;
    u32 nib = (u32)(pbits[q >> 4] >> ((q & 15u) << 2)) & 0xFu;
    float4 s4 = *(const float4*)(sim + q * 4u);
    float ss[4] = {s4.x, s4.y, s4.z, s4.w};
#pragma unroll
    for (int j = 0; j < 4; j++){
      if (!((nib >> j) & 1u)){
        u32 key = sortkey(ss[j]);
        if ((key >> 21) == p1) atomicAdd(&lh[(key >> 10) & 2047u], 1u);
      }
    }
  }
  __syncthreads();
  for (u32 i = threadIdx.x; i < 2048u; i += 256u)
    if (lh[i]) atomicAdd(&h2[i], lh[i]);
}

// ---------- mark top-250 seeds (22-bit prefix + ticket for the boundary bucket) ----------
__global__ __launch_bounds__(256) void k_mark(const float* __restrict__ sim,
                                              const u64* __restrict__ pbits,
                                              u64* __restrict__ hs,
                                              const u32* __restrict__ h1,
                                              const u32* __restrict__ h2,
                                              Ctrl* ctrl){
  __shared__ u32 shres[2];
  u32 p1, k1, b2, k2;
  select_top(h1, 2048, TOPN, shres, &p1, &k1);
  select_top(h2, 2048, k1, shres, &b2, &k2);
  u32 p12 = (p1 << 11) | b2;
  int lane = threadIdx.x & 63;
  const u32 stride = 1024u * 256u;
#pragma unroll 1
  for (u32 it = 0; it < 8; it++){
    u32 v = blockIdx.x * 256u + threadIdx.x + it * stride;
    u64 w = pbits[v >> 6];
    bool neg = !((w >> (v & 63u)) & 1ull);
    bool seed = false;
    if (neg){
      u32 pref = sortkey(sim[v]) >> 10;
      if (pref > p12) seed = true;
      else if (pref == p12){
        u32 old = atomicAdd(&ctrl->tie, 1u);
        if (old < k2) seed = true;
      }
    }
    u64 mb = __ballot(seed);
    if (lane == 0) hs[v >> 6] = mb;
  }
}

// ---------- final: inline D-dilation of both masks + mis/fin sums + combine ----------
__global__ __launch_bounds__(256) void k_final(const float* __restrict__ sim,
                                               const u64* __restrict__ P,
                                               const u64* __restrict__ T1P,
                                               const u64* __restrict__ T1H,
                                               Acc* acc, Ctrl* ctrl, float* out){
  __shared__ float shf[4]; __shared__ u32 shu[4];
  __shared__ int amLast;
  u32 wi = blockIdx.x * 256u + threadIdx.x;   // one 64-voxel word per thread
  u32 wj = wi & 1u;
  u32 row = wi >> 1;                           // b*8192 + d*128 + h
  int h = (int)(row & 127u);
  int d = (int)((row >> 7) & 63u);
  u32 b = row >> 13;
  int d0 = d - 10 > 0 ? d - 10 : 0;
  int d1 = d + 10 < 63 ? d + 10 : 63;
  const u64* bp = T1P + ((size_t)(b << 13) + (u32)h) * 2 + wj;
  const u64* bh = T1H + ((size_t)(b << 13) + (u32)h) * 2 + wj;
  u64 dpw = 0, dhw = 0;
  for (int dd = d0; dd <= d1; dd++){
    dpw |= bp[(size_t)dd * 256];
    dhw |= bh[(size_t)dd * 256];
  }
  u64 pw = P[wi];
  u64 mis = dpw & ~pw;
  u64 fin = dhw & ~pw;
  float mn = 0.f, fnm = 0.f;
  u32 mc = (u32)__popcll(mis), fc = (u32)__popcll(fin);
  const float* sp = sim + (size_t)wi * 64u;
#pragma unroll 1
  for (int jj = 0; jj < 16; jj++){
    float4 s4 = *(const float4*)(sp + jj * 4);
    float ss[4] = {s4.x, s4.y, s4.z, s4.w};
#pragma unroll
    for (int j = 0; j < 4; j++){
      int bit = jj * 4 + j;
      float r = fmaxf(ss[j], 0.f);
      if ((mis >> bit) & 1ull) mn += r;
      if ((fin >> bit) & 1ull) fnm += r;
    }
  }
  red_d(&acc->mis_num, mn, shf);
  red_d(&acc->fin_num, fnm, shf);
  red_u(&acc->mcnt, mc, shu);
  red_u(&acc->fcnt, fc, shu);
  __threadfence();
  if (threadIdx.x == 0) amLast = (atomicAdd(&ctrl->done4, 1u) == gridDim.x - 1);
  __syncthreads();
  if (amLast && threadIdx.x == 0){
    double ce = acc->ce / (double)NN;
    double tp = acc->tp, fp = acc->fp, fn = acc->fn;
    double dc1 = (2.0 * tp + 1e-5) / (2.0 * tp + fp + fn + 1e-5 + 1e-8);
    u64 cnt = acc->cnt;
    double pos_loss = cnt ? (acc->pos_num / (double)cnt) : 0.0;
    u64 mcnt = atomicAdd(&acc->mcnt, 0ull);
    u64 fcnt = atomicAdd(&acc->fcnt, 0ull);
    double mis_loss = mcnt ? (atomicAdd(&acc->mis_num, 0.0) / (double)mcnt) : 0.0;
    double neg_loss = fcnt ? (atomicAdd(&acc->fin_num, 0.0) / (double)fcnt) : 0.0;
    out[0] = (float)(ce - dc1 + 5.0 * (pos_loss + mis_loss + neg_loss));
  }
}

extern "C" void kernel_launch(void* const* d_in, const int* in_sizes, int n_in,
                              void* d_out, int out_size, void* d_ws, size_t ws_size,
                              hipStream_t stream){
  (void)in_sizes; (void)n_in; (void)out_size; (void)ws_size;
  const float* feat = (const float*)d_in[0];
  const float* net  = (const float*)d_in[1];
  const int*   tgt  = (const int*)d_in[2];
  float* out = (float*)d_out;
  char* ws = (char*)d_ws;

  size_t off = 0;
  auto take = [&](size_t bytes) -> void* {
    void* p = (void*)(ws + off);
    off += (bytes + 255) & ~(size_t)255;
    return p;
  };
  float* sim = (float*)take((size_t)NN * 4);
  u64* P   = (u64*)take((size_t)NWORDS * 8);
  u64* T1P = (u64*)take((size_t)NWORDS * 8);
  u64* HS  = (u64*)take((size_t)NWORDS * 8);
  u64* T1H = (u64*)take((size_t)NWORDS * 8);
  u32* cntArr = (u32*)take(512 * 4);
  size_t zstart = off;
  u32* h1 = (u32*)take(2048 * 4);
  u32* h2 = (u32*)take(2048 * 4);
  Ctrl* ctrl = (Ctrl*)take(sizeof(Ctrl));
  Acc* acc = (Acc*)take(sizeof(Acc));
  u32 zwords = (u32)((off - zstart) >> 2);

  // 7 dispatches (was 8): memset folded into k_pre, CE fused into the std pass.
  k_pre<<<512, 256, 0, stream>>>(tgt, P, cntArr, (u32*)(ws + zstart), zwords);
  k_ce_std<<<1088, 256, 0, stream>>>(feat, net, P, acc);
  k_sim<<<512, 256, 0, stream>>>(feat, P, cntArr, acc, sim, h1);
  k_histL2<<<512, 256, 0, stream>>>(sim, P, h1, h2, P, T1P);
  k_mark<<<1024, 256, 0, stream>>>(sim, P, HS, h1, h2, ctrl);
  k_dilwh<<<128, 256, 0, stream>>>(HS, T1H);
  k_final<<<128, 256, 0, stream>>>(sim, P, T1P, T1H, acc, ctrl, out);
}

// Round 2
// 486.965 us; speedup vs baseline: 1.0962x; 1.0002x over previous
//
#include <hip/hip_runtime.h>
#include <stdint.h>

typedef unsigned int u32;
typedef unsigned long long u64;
typedef float f4v __attribute__((ext_vector_type(4)));
typedef int i4v __attribute__((ext_vector_type(4)));

#define BB 2
#define CC 32
#define DD 64
#define HH 128
#define WW 128
#define SS (DD*HH*WW)        /* 1048576 */
#define NN (BB*SS)           /* 2097152 */
#define NQ (NN/4)            /* 524288 */
#define NWORDS (NN/64)       /* 32768 */
#define EPSF 1e-12f
#define TOPN 250u

struct Ctrl {
  u32 done4, tie, pad0, pad1;
};

struct Acc {
  double ce, tp, fp, fn;
  double stdsum[CC];
  double pos_num, mis_num, fin_num;
  u64 cnt, mcnt, fcnt;
};

// ---------- reduction helpers ----------
__device__ __forceinline__ float waveRedF(float v){
#pragma unroll
  for (int o = 32; o; o >>= 1) v += __shfl_xor(v, o);
  return v;
}
__device__ __forceinline__ u32 waveRedU(u32 v){
#pragma unroll
  for (int o = 32; o; o >>= 1) v += __shfl_xor(v, o);
  return v;
}
__device__ __forceinline__ void red_d(double* dst, float v, volatile float* sh){
  int lane = threadIdx.x & 63, wid = threadIdx.x >> 6;
  v = waveRedF(v);
  if (lane == 0) sh[wid] = v;
  __syncthreads();
  if (threadIdx.x == 0){
    float t = 0.f;
    for (int i = 0; i < (int)(blockDim.x >> 6); i++) t += sh[i];
    atomicAdd(dst, (double)t);
  }
  __syncthreads();
}
__device__ __forceinline__ void red_u(u64* dst, u32 v, volatile u32* sh){
  int lane = threadIdx.x & 63, wid = threadIdx.x >> 6;
  v = waveRedU(v);
  if (lane == 0) sh[wid] = v;
  __syncthreads();
  if (threadIdx.x == 0){
    u32 t = 0;
    for (int i = 0; i < (int)(blockDim.x >> 6); i++) t += sh[i];
    atomicAdd(dst, (u64)t);
  }
  __syncthreads();
}

__device__ __forceinline__ u32 sortkey(float f){
  u32 u = __float_as_uint(f);
  return (u & 0x80000000u) ? ~u : (u | 0x80000000u);
}

// Redundant per-block top-k bin selection from a finalized global histogram.
__device__ __forceinline__ void select_top(const u32* __restrict__ hist, u32 nbins,
                                           u32 k, u32* shres, u32* binOut, u32* kremOut){
  __syncthreads();
  if (threadIdx.x < 64){
    int lane = threadIdx.x;
    u32 running = 0; bool found = false;
    for (u32 chunk = 0; chunk * 64 < nbins && !found; chunk++){
      int bin = (int)nbins - 1 - (int)(chunk * 64 + (u32)lane);
      u32 val = (bin >= 0) ? hist[bin] : 0u;
      u32 p = val;
#pragma unroll
      for (int o = 1; o < 64; o <<= 1){ u32 t = __shfl_up(p, o); if (lane >= o) p += t; }
      u32 tot = __shfl(p, 63);
      u32 incl = running + p, excl = incl - val;
      bool hit = (excl < k) && (incl >= k);
      u64 mb = __ballot(hit);
      if (mb){
        int hl = __ffsll((unsigned long long)mb) - 1;
        if (lane == hl){ shres[0] = (u32)bin; shres[1] = k - excl; }
        found = true;
      } else running += tot;
    }
    if (!found && lane == 0){ shres[0] = 0; shres[1] = k; }
  }
  __syncthreads();
  *binOut = shres[0]; *kremOut = shres[1];
}

// ---------- K0: pbits from tgt + per-block pos counts + zero accumulators ----------
// grid 512 x 256. Each block packs 4096 voxels -> 64 u64 words.
// tgt is read-once: non-temporal load keeps L3 clean for the feature stream.
__global__ __launch_bounds__(256) void k_pre(const int* __restrict__ tgt,
                                             u64* __restrict__ pbits,
                                             u32* __restrict__ cntArr,
                                             u32* __restrict__ zptr, u32 zwords){
  __shared__ u32 nibsh[256];
  __shared__ u32 shu[4];
  if (blockIdx.x == 0){
    for (u32 i = threadIdx.x; i < zwords; i += 256u) zptr[i] = 0;
  }
  u32 cnt = 0;
#pragma unroll 1
  for (u32 it = 0; it < 4; it++){
    u32 q = blockIdx.x * 1024u + it * 256u + threadIdx.x;   // quad index
    i4v l4 = __builtin_nontemporal_load((const i4v*)(tgt + q * 4u));
    u32 nib = (l4.x ? 1u : 0u) | (l4.y ? 2u : 0u) | (l4.z ? 4u : 0u) | (l4.w ? 8u : 0u);
    cnt += __popc(nib);
    __syncthreads();             // protect nibsh reuse across iterations
    nibsh[threadIdx.x] = nib;
    __syncthreads();
    if (threadIdx.x < 16){
      u64 o = 0;
#pragma unroll
      for (int j = 0; j < 16; j++)
        o |= (u64)(nibsh[threadIdx.x * 16 + j] & 0xFu) << (4 * j);
      pbits[blockIdx.x * 64u + it * 16u + threadIdx.x] = o;
    }
  }
  int lane = threadIdx.x & 63, wid = threadIdx.x >> 6;
  cnt = waveRedU(cnt);
  if (lane == 0) shu[wid] = cnt;
  __syncthreads();
  if (threadIdx.x == 0) cntArr[blockIdx.x] = shu[0] + shu[1] + shu[2] + shu[3];
}

// ---------- K1: fused CE/dice + channel-major pos-sum of feature ----------
// Blocks 0..63: CE/dice over net (16 MB, non-temporal -> no L3 pollution).
// Blocks 64..1087: std pos-sums, each reading a SEQUENTIAL 256-KB feature run
// in ASCENDING chunk order -> at kernel end, L3 holds the TAIL of feat.
__global__ __launch_bounds__(256) void k_ce_std(const float* __restrict__ feat,
                                                const float* __restrict__ net,
                                                const u64* __restrict__ pbits, Acc* acc){
  __shared__ float sh[16];
  if (blockIdx.x < 64u){
    u32 bid = blockIdx.x;
    float ce = 0.f, tp = 0.f, fp = 0.f, fnn = 0.f;
#pragma unroll 1
    for (u32 it = 0; it < 32; it++){
      u32 q = bid * 8192u + it * 256u + threadIdx.x;        // quad index
      u32 nib = (u32)(pbits[q >> 4] >> ((q & 15u) << 2)) & 0xFu;
      u32 v = q * 4u;
      u32 b = v >> 20, s = v & (SS - 1);
      const float* nb = net + (size_t)(b * 2) * SS + s;
      f4v x0 = __builtin_nontemporal_load((const f4v*)(nb));
      f4v x1 = __builtin_nontemporal_load((const f4v*)(nb + SS));
      float xs0[4] = {x0.x, x0.y, x0.z, x0.w};
      float xs1[4] = {x1.x, x1.y, x1.z, x1.w};
#pragma unroll
      for (int j = 0; j < 4; j++){
        int lab = (nib >> j) & 1;
        float m = fmaxf(xs0[j], xs1[j]);
        float lse = m + logf(expf(xs0[j] - m) + expf(xs1[j] - m));
        ce += lse - (lab ? xs1[j] : xs0[j]);
        float p1 = expf(xs1[j] - lse);
        if (lab){ tp += p1; fnn += 1.0f - p1; } else fp += p1;
      }
    }
    int lane = threadIdx.x & 63, wid = threadIdx.x >> 6;
    ce = waveRedF(ce); tp = waveRedF(tp); fp = waveRedF(fp); fnn = waveRedF(fnn);
    if (lane == 0){ sh[wid] = ce; sh[4 + wid] = tp; sh[8 + wid] = fp; sh[12 + wid] = fnn; }
    __syncthreads();
    if (threadIdx.x == 0){
      atomicAdd(&acc->ce, (double)(sh[0] + sh[1] + sh[2] + sh[3]));
      atomicAdd(&acc->tp, (double)(sh[4] + sh[5] + sh[6] + sh[7]));
      atomicAdd(&acc->fp, (double)(sh[8] + sh[9] + sh[10] + sh[11]));
      atomicAdd(&acc->fn, (double)(sh[12] + sh[13] + sh[14] + sh[15]));
    }
  } else {
    u32 bx = blockIdx.x - 64u;
    u32 c = bx & 31u;
    u32 chunk = bx >> 5;                // 0..31, ascending
    u32 vbase = chunk * 65536u;
    u32 b = vbase >> 20;
    u32 s0 = vbase & (SS - 1);
    const float* fp_ = feat + (size_t)b * CC * SS + (size_t)c * SS + s0;
    const u64* pb = pbits + (vbase >> 6);
    float a = 0.f;
#pragma unroll 8
    for (u32 i = 0; i < 64; i++){
      u32 off = i * 1024u + threadIdx.x * 4u;
      float4 f = *(const float4*)(fp_ + off);
      u32 bits = (u32)(pb[off >> 6] >> (off & 63u)) & 0xFu;
      if (bits & 1u) a += f.x;
      if (bits & 2u) a += f.y;
      if (bits & 4u) a += f.z;
      if (bits & 8u) a += f.w;
    }
    int lane = threadIdx.x & 63, wid = threadIdx.x >> 6;
    a = waveRedF(a);
    if (lane == 0) sh[wid] = a;
    __syncthreads();
    if (threadIdx.x == 0)
      atomicAdd(&acc->stdsum[c], (double)(sh[0] + sh[1] + sh[2] + sh[3]));
  }
}

// ---------- K3: sim via register-blocked channel-outer loop ----------
// Each block owns 4096 voxels; per channel it reads a dense 16-KB window.
// REVERSED block order: pass 2 consumes the most-recently-streamed feat
// chunks first, so the L3-resident tail from k_ce_std is hit at L3 BW
// instead of refetched from HBM. L3 hits don't evict, so the resident
// window survives as we walk backward.
__global__ __launch_bounds__(256) void k_sim(const float* __restrict__ feat,
                                             const u64* __restrict__ pbits,
                                             const u32* __restrict__ cntArr,
                                             Acc* acc, float* __restrict__ sim,
                                             u32* __restrict__ h1){
  __shared__ float st[CC];
  __shared__ u32 lh[2048];
  __shared__ float shf[4];
  __shared__ u32 scnt;
  if (threadIdx.x < 64){
    u32 sc = 0;
#pragma unroll
    for (int i = 0; i < 8; i++) sc += cntArr[threadIdx.x * 8 + i];
    sc = waveRedU(sc);
    if (threadIdx.x == 0) scnt = sc;
  }
  __syncthreads();
  u32 cnt = scnt;
  if (blockIdx.x == 0 && threadIdx.x == 0) acc->cnt = (u64)cnt;
  {
    float sv = 0.f;
    if (threadIdx.x < CC && cnt) sv = (float)(acc->stdsum[threadIdx.x] / (double)cnt);
    if (threadIdx.x < 64){
      float t = waveRedF(sv * sv);
      float d = fmaxf(sqrtf(t), EPSF);
      if (threadIdx.x < CC) st[threadIdx.x] = sv / d;
    }
  }
  for (u32 i = threadIdx.x; i < 2048u; i += 256u) lh[i] = 0;
  __syncthreads();
  u32 vbase = (511u - blockIdx.x) * 4096u;    // reversed for L3 reuse
  u32 b = vbase >> 20;
  u32 s0 = vbase & (SS - 1);
  const float* fp = feat + (size_t)b * CC * SS + s0;
  float4 dt[4], n2[4];
#pragma unroll
  for (int g = 0; g < 4; g++){
    dt[g].x = dt[g].y = dt[g].z = dt[g].w = 0.f;
    n2[g].x = n2[g].y = n2[g].z = n2[g].w = 0.f;
  }
#pragma unroll 2
  for (u32 c = 0; c < CC; c++){
    float w = st[c];
    const float* fc = fp + (size_t)c * SS;
    float4 f[4];
#pragma unroll
    for (int g = 0; g < 4; g++)
      f[g] = *(const float4*)(fc + (u32)g * 1024u + threadIdx.x * 4u);
#pragma unroll
    for (int g = 0; g < 4; g++){
      dt[g].x += f[g].x * w; dt[g].y += f[g].y * w;
      dt[g].z += f[g].z * w; dt[g].w += f[g].w * w;
      n2[g].x += f[g].x * f[g].x; n2[g].y += f[g].y * f[g].y;
      n2[g].z += f[g].z * f[g].z; n2[g].w += f[g].w * f[g].w;
    }
  }
  float pn = 0.f;
#pragma unroll
  for (int g = 0; g < 4; g++){
    u32 off = (u32)g * 1024u + threadIdx.x * 4u;
    u32 v = vbase + off;
    float4 sm;
    sm.x = dt[g].x / fmaxf(sqrtf(n2[g].x), EPSF);
    sm.y = dt[g].y / fmaxf(sqrtf(n2[g].y), EPSF);
    sm.z = dt[g].z / fmaxf(sqrtf(n2[g].z), EPSF);
    sm.w = dt[g].w / fmaxf(sqrtf(n2[g].w), EPSF);
    *(float4*)(sim + v) = sm;
    u32 bits = (u32)(pbits[v >> 6] >> (v & 63u)) & 0xFu;
    float ss[4] = {sm.x, sm.y, sm.z, sm.w};
#pragma unroll
    for (int j = 0; j < 4; j++){
      if ((bits >> j) & 1u) pn += 1.f - ss[j];
      else atomicAdd(&lh[sortkey(ss[j]) >> 21], 1u);
    }
  }
  __syncthreads();
  for (u32 i = threadIdx.x; i < 2048u; i += 256u)
    if (lh[i]) atomicAdd(&h1[i], lh[i]);
  red_d(&acc->pos_num, pn, shf);
}

// ---------- fused W+H slab dilation as a device function ----------
__device__ __forceinline__ void dilwh_slab(const u64* __restrict__ in, u64* __restrict__ out,
                                           u32 slab, u64* arr){
  u32 base = slab * 256u;
  int t = threadIdx.x;
  if (t < 128){
    u64 lo = in[base + 2 * t], hi = in[base + 2 * t + 1];
    u64 al = lo, ah = hi;
#pragma unroll
    for (int i = 0; i < 10; i++){ u64 c = al >> 63; ah = ah | (ah << 1) | c; al = al | (al << 1); }
    u64 bl = lo, bh = hi;
#pragma unroll
    for (int i = 0; i < 10; i++){ u64 c = bh << 63; bl = bl | (bl >> 1) | c; bh = bh | (bh >> 1); }
    arr[2 * t] = al | bl;
    arr[2 * t + 1] = ah | bh;
  }
  __syncthreads();
  int h = t >> 1, wj = t & 1;
  int h0 = h - 10 > 0 ? h - 10 : 0;
  int h1 = h + 10 < 127 ? h + 10 : 127;
  u64 o = 0;
  for (int hh = h0; hh <= h1; hh++) o |= arr[2 * hh + wj];
  out[base + (u32)t] = o;
  __syncthreads();
}

// ---------- W+H dilation standalone (for HS) ----------
__global__ __launch_bounds__(256) void k_dilwh(const u64* __restrict__ in, u64* __restrict__ out){
  __shared__ u64 arr[256];
  dilwh_slab(in, out, blockIdx.x, arr);
}

// ---------- level-2 histogram + (blocks<128) W+H dilation of P ----------
__global__ __launch_bounds__(256) void k_histL2(const float* __restrict__ sim,
                                                const u64* __restrict__ pbits,
                                                const u32* __restrict__ h1,
                                                u32* __restrict__ h2,
                                                const u64* __restrict__ P,
                                                u64* __restrict__ T1P){
  __shared__ u64 arr[256];
  __shared__ u32 lh[2048];
  __shared__ u32 shres[2];
  if (blockIdx.x < 128u) dilwh_slab(P, T1P, blockIdx.x, arr);
  u32 p1, k1;
  select_top(h1, 2048, TOPN, shres, &p1, &k1);
  for (u32 i = threadIdx.x; i < 2048u; i += 256u) lh[i] = 0;
  __syncthreads();
  const u32 stride = 512u * 256u;
#pragma unroll 1
  for (u32 it = 0; it < 4; it++){
    u32 q = blockIdx.x * 256u + threadIdx.x + it * stride;
    u32 nib = (u32)(pbits[q >> 4] >> ((q & 15u) << 2)) & 0xFu;
    float4 s4 = *(const float4*)(sim + q * 4u);
    float ss[4] = {s4.x, s4.y, s4.z, s4.w};
#pragma unroll
    for (int j = 0; j < 4; j++){
      if (!((nib >> j) & 1u)){
        u32 key = sortkey(ss[j]);
        if ((key >> 21) == p1) atomicAdd(&lh[(key >> 10) & 2047u], 1u);
      }
    }
  }
  __syncthreads();
  for (u32 i = threadIdx.x; i < 2048u; i += 256u)
    if (lh[i]) atomicAdd(&h2[i], lh[i]);
}

// ---------- mark top-250 seeds (22-bit prefix + ticket for the boundary bucket) ----------
__global__ __launch_bounds__(256) void k_mark(const float* __restrict__ sim,
                                              const u64* __restrict__ pbits,
                                              u64* __restrict__ hs,
                                              const u32* __restrict__ h1,
                                              const u32* __restrict__ h2,
                                              Ctrl* ctrl){
  __shared__ u32 shres[2];
  u32 p1, k1, b2, k2;
  select_top(h1, 2048, TOPN, shres, &p1, &k1);
  select_top(h2, 2048, k1, shres, &b2, &k2);
  u32 p12 = (p1 << 11) | b2;
  int lane = threadIdx.x & 63;
  const u32 stride = 1024u * 256u;
#pragma unroll 1
  for (u32 it = 0; it < 8; it++){
    u32 v = blockIdx.x * 256u + threadIdx.x + it * stride;
    u64 w = pbits[v >> 6];
    bool neg = !((w >> (v & 63u)) & 1ull);
    bool seed = false;
    if (neg){
      u32 pref = sortkey(sim[v]) >> 10;
      if (pref > p12) seed = true;
      else if (pref == p12){
        u32 old = atomicAdd(&ctrl->tie, 1u);
        if (old < k2) seed = true;
      }
    }
    u64 mb = __ballot(seed);
    if (lane == 0) hs[v >> 6] = mb;
  }
}

// ---------- final: inline D-dilation of both masks + mis/fin sums + combine ----------
__global__ __launch_bounds__(256) void k_final(const float* __restrict__ sim,
                                               const u64* __restrict__ P,
                                               const u64* __restrict__ T1P,
                                               const u64* __restrict__ T1H,
                                               Acc* acc, Ctrl* ctrl, float* out){
  __shared__ float shf[4]; __shared__ u32 shu[4];
  __shared__ int amLast;
  u32 wi = blockIdx.x * 256u + threadIdx.x;   // one 64-voxel word per thread
  u32 wj = wi & 1u;
  u32 row = wi >> 1;                           // b*8192 + d*128 + h
  int h = (int)(row & 127u);
  int d = (int)((row >> 7) & 63u);
  u32 b = row >> 13;
  int d0 = d - 10 > 0 ? d - 10 : 0;
  int d1 = d + 10 < 63 ? d + 10 : 63;
  const u64* bp = T1P + ((size_t)(b << 13) + (u32)h) * 2 + wj;
  const u64* bh = T1H + ((size_t)(b << 13) + (u32)h) * 2 + wj;
  u64 dpw = 0, dhw = 0;
  for (int dd = d0; dd <= d1; dd++){
    dpw |= bp[(size_t)dd * 256];
    dhw |= bh[(size_t)dd * 256];
  }
  u64 pw = P[wi];
  u64 mis = dpw & ~pw;
  u64 fin = dhw & ~pw;
  float mn = 0.f, fnm = 0.f;
  u32 mc = (u32)__popcll(mis), fc = (u32)__popcll(fin);
  const float* sp = sim + (size_t)wi * 64u;
#pragma unroll 1
  for (int jj = 0; jj < 16; jj++){
    float4 s4 = *(const float4*)(sp + jj * 4);
    float ss[4] = {s4.x, s4.y, s4.z, s4.w};
#pragma unroll
    for (int j = 0; j < 4; j++){
      int bit = jj * 4 + j;
      float r = fmaxf(ss[j], 0.f);
      if ((mis >> bit) & 1ull) mn += r;
      if ((fin >> bit) & 1ull) fnm += r;
    }
  }
  red_d(&acc->mis_num, mn, shf);
  red_d(&acc->fin_num, fnm, shf);
  red_u(&acc->mcnt, mc, shu);
  red_u(&acc->fcnt, fc, shu);
  __threadfence();
  if (threadIdx.x == 0) amLast = (atomicAdd(&ctrl->done4, 1u) == gridDim.x - 1);
  __syncthreads();
  if (amLast && threadIdx.x == 0){
    double ce = acc->ce / (double)NN;
    double tp = acc->tp, fp = acc->fp, fn = acc->fn;
    double dc1 = (2.0 * tp + 1e-5) / (2.0 * tp + fp + fn + 1e-5 + 1e-8);
    u64 cnt = acc->cnt;
    double pos_loss = cnt ? (acc->pos_num / (double)cnt) : 0.0;
    u64 mcnt = atomicAdd(&acc->mcnt, 0ull);
    u64 fcnt = atomicAdd(&acc->fcnt, 0ull);
    double mis_loss = mcnt ? (atomicAdd(&acc->mis_num, 0.0) / (double)mcnt) : 0.0;
    double neg_loss = fcnt ? (atomicAdd(&acc->fin_num, 0.0) / (double)fcnt) : 0.0;
    out[0] = (float)(ce - dc1 + 5.0 * (pos_loss + mis_loss + neg_loss));
  }
}

extern "C" void kernel_launch(void* const* d_in, const int* in_sizes, int n_in,
                              void* d_out, int out_size, void* d_ws, size_t ws_size,
                              hipStream_t stream){
  (void)in_sizes; (void)n_in; (void)out_size; (void)ws_size;
  const float* feat = (const float*)d_in[0];
  const float* net  = (const float*)d_in[1];
  const int*   tgt  = (const int*)d_in[2];
  float* out = (float*)d_out;
  char* ws = (char*)d_ws;

  size_t off = 0;
  auto take = [&](size_t bytes) -> void* {
    void* p = (void*)(ws + off);
    off += (bytes + 255) & ~(size_t)255;
    return p;
  };
  float* sim = (float*)take((size_t)NN * 4);
  u64* P   = (u64*)take((size_t)NWORDS * 8);
  u64* T1P = (u64*)take((size_t)NWORDS * 8);
  u64* HS  = (u64*)take((size_t)NWORDS * 8);
  u64* T1H = (u64*)take((size_t)NWORDS * 8);
  u32* cntArr = (u32*)take(512 * 4);
  size_t zstart = off;
  u32* h1 = (u32*)take(2048 * 4);
  u32* h2 = (u32*)take(2048 * 4);
  Ctrl* ctrl = (Ctrl*)take(sizeof(Ctrl));
  Acc* acc = (Acc*)take(sizeof(Acc));
  u32 zwords = (u32)((off - zstart) >> 2);

  // 7 dispatches: memset folded into k_pre, CE fused into the std pass.
  k_pre<<<512, 256, 0, stream>>>(tgt, P, cntArr, (u32*)(ws + zstart), zwords);
  k_ce_std<<<1088, 256, 0, stream>>>(feat, net, P, acc);
  k_sim<<<512, 256, 0, stream>>>(feat, P, cntArr, acc, sim, h1);
  k_histL2<<<512, 256, 0, stream>>>(sim, P, h1, h2, P, T1P);
  k_mark<<<1024, 256, 0, stream>>>(sim, P, HS, h1, h2, ctrl);
  k_dilwh<<<128, 256, 0, stream>>>(HS, T1H);
  k_final<<<128, 256, 0, stream>>>(sim, P, T1P, T1H, acc, ctrl, out);
}